// Round 1
// baseline (424.027 us; speedup 1.0000x reference)
//
#include <hip/hip_runtime.h>

// LIF layer: v_pre = a*v + (1-a)*i ; z = 10*(v_pre-0.25) ; s = (v_pre>=0.25);
// v = s ? 0 : v_pre.  One thread per (b,f) row, sequential scan over L=1024.
// Memory-bound: 384 MiB total traffic -> ~64us floor at 6.3 TB/s.

constexpr int L_LEN = 1024;

__global__ __launch_bounds__(64) void lif_kernel(
    const float* __restrict__ I, float* __restrict__ Z,
    float* __restrict__ S, int nrows)
{
#pragma clang fp contract(off)
    int row = blockIdx.x * 64 + threadIdx.x;
    if (row >= nrows) return;

    const float alpha = 0.7165313105737893f;   // exp(-1/3) rounded to f32
    const float oma   = 1.0f - alpha;
    const float thr   = 0.25f;
    const float beta  = 10.0f;

    const float4* in4 = reinterpret_cast<const float4*>(I) + (size_t)row * (L_LEN / 4);
    float4*       z4  = reinterpret_cast<float4*>(Z)       + (size_t)row * (L_LEN / 4);
    float4*       s4  = reinterpret_cast<float4*>(S)       + (size_t)row * (L_LEN / 4);

    float v = 0.0f;
#pragma unroll 8
    for (int t = 0; t < L_LEN / 4; ++t) {
        float4 x = in4[t];
        float4 zo, so;
        float vp;

        vp = alpha * v + oma * x.x;
        zo.x = beta * (vp - thr);
        so.x = (vp >= thr) ? 1.0f : 0.0f;
        v    = (vp >= thr) ? 0.0f : vp;

        vp = alpha * v + oma * x.y;
        zo.y = beta * (vp - thr);
        so.y = (vp >= thr) ? 1.0f : 0.0f;
        v    = (vp >= thr) ? 0.0f : vp;

        vp = alpha * v + oma * x.z;
        zo.z = beta * (vp - thr);
        so.z = (vp >= thr) ? 1.0f : 0.0f;
        v    = (vp >= thr) ? 0.0f : vp;

        vp = alpha * v + oma * x.w;
        zo.w = beta * (vp - thr);
        so.w = (vp >= thr) ? 1.0f : 0.0f;
        v    = (vp >= thr) ? 0.0f : vp;

        z4[t] = zo;
        s4[t] = so;
    }
}

extern "C" void kernel_launch(void* const* d_in, const int* in_sizes, int n_in,
                              void* d_out, int out_size, void* d_ws, size_t ws_size,
                              hipStream_t stream) {
    const float* I = (const float*)d_in[0];
    int n_elems = in_sizes[0];          // B*F*L = 33554432
    int nrows   = n_elems / L_LEN;      // B*F   = 32768

    float* Z = (float*)d_out;                       // first output, flat (B,F,L)
    float* S = (float*)d_out + (size_t)n_elems;     // second output

    int block = 64;                                  // 512 blocks -> 2 waves/CU on all 256 CUs
    int grid  = (nrows + block - 1) / block;
    lif_kernel<<<grid, block, 0, stream>>>(I, Z, S, nrows);
}